// Round 2
// baseline (1514.536 us; speedup 1.0000x reference)
//
#include <hip/hip_runtime.h>

// Natural cubic spline coefficients (Habermann-Kindermann), 3 axis sweeps.
// tridiag(1,4,1) inverse decays as (2-sqrt(3))^|i-j| -> banded conv, K=16.

#define KHW 16
#define NTAPS 33   // 2*KHW+1
#define MSOL 255   // system size n-1, n=256

// Build the 255x33 banded inverse-weight table in fp64.
// Tinv[i][t] (0-indexed) = (-1)^(i+t) * th[min] * th[254-max] / th[255],
// th_k = 4 th_{k-1} - th_{k-2}, th_0=1, th_1=4.
__global__ void build_w_kernel(float* __restrict__ W) {
    __shared__ double th[256];
    if (threadIdx.x == 0) {
        th[0] = 1.0; th[1] = 4.0;
        for (int k = 2; k < 256; ++k) th[k] = 4.0 * th[k - 1] - th[k - 2];
    }
    __syncthreads();
    const double thm = th[255];
    for (int idx = threadIdx.x; idx < MSOL * NTAPS; idx += blockDim.x) {
        int i  = idx / NTAPS;
        int kk = idx - i * NTAPS;
        int t  = i + kk - KHW;
        float val = 0.f;
        if (t >= 0 && t < MSOL) {
            int a = i < t ? i : t;
            int b = i < t ? t : i;
            double v = th[a] * th[254 - b] / thm;
            if ((i + t) & 1) v = -v;
            val = (float)v;
        }
        W[idx] = val;
    }
}

// One spline sweep along the middle axis of a (P, 257, Q) array -> (P, 259, Q).
// One thread per OUTPUT element. P, Q compile-time so / and % are magic-muls.
template <int P, int Q>
__global__ __launch_bounds__(256) void sweep_kernel(const float* __restrict__ in,
                                                    float* __restrict__ out,
                                                    const float* __restrict__ W) {
    constexpr int NO  = 259;
    constexpr int TOT = P * NO * Q;
    int tid = blockIdx.x * 256 + threadIdx.x;
    if (tid >= TOT) return;

    int q   = tid % Q;
    int rem = tid / Q;
    int j   = rem % NO;
    int p   = rem / NO;

    const float* __restrict__ y = in + (size_t)p * 257 * Q + q;
    const float sixth = 1.0f / 6.0f;

    float res;
    if (j == 1) {
        res = y[0] * sixth;                         // c[1] = b1
    } else if (j == 257) {
        res = y[(size_t)256 * Q] * sixth;           // c[n+1] = b2
    } else {
        // sol row needed: j==0 -> row 0, j==258 -> row 254, else j-2
        int i = (j == 0) ? 0 : ((j == 258) ? MSOL - 1 : j - 2);
        int t0 = i - KHW; if (t0 < 0) t0 = 0;
        int t1 = i + KHW; if (t1 > MSOL - 1) t1 = MSOL - 1;
        const float* __restrict__ w = W + i * NTAPS;
        float s = 0.f;
        for (int t = t0; t <= t1; ++t) {
            float b = y[(size_t)(t + 1) * Q];       // B[t] = y[t+1] (+end fixups)
            if (t == 0)        b -= y[0] * sixth;
            if (t == MSOL - 1) b -= y[(size_t)256 * Q] * sixth;
            s = fmaf(w[t - i + KHW], b, s);
        }
        if (j == 0)        res = 2.f * (y[0] * sixth) - s;             // 2 b1 - sol[0]
        else if (j == 258) res = 2.f * (y[(size_t)256 * Q] * sixth) - s; // 2 b2 - sol[254]
        else               res = s;
    }
    out[tid] = res;   // tid == p*NO*Q + j*Q + q, the output index
}

extern "C" void kernel_launch(void* const* d_in, const int* in_sizes, int n_in,
                              void* d_out, int out_size, void* d_ws, size_t ws_size,
                              hipStream_t stream) {
    const float* Y = (const float*)d_in[0];
    float* out = (float*)d_out;
    float* W   = (float*)d_ws;
    float* A2  = (float*)((char*)d_ws + (1 << 20));  // intermediate #2, after W table

    build_w_kernel<<<1, 256, 0, stream>>>(W);

    constexpr int NO = 259;
    {   // axis 0: (257,257,257) -> (259,257,257), into d_out (scratch)
        constexpr int P = 1, Q = 257 * 257;
        constexpr int tot = P * NO * Q;
        sweep_kernel<P, Q><<<(tot + 255) / 256, 256, 0, stream>>>(Y, out, W);
    }
    {   // axis 1: (259,257,257) -> (259,259,257), into ws
        constexpr int P = 259, Q = 257;
        constexpr int tot = P * NO * Q;
        sweep_kernel<P, Q><<<(tot + 255) / 256, 256, 0, stream>>>(out, A2, W);
    }
    {   // axis 2: (259,259,257) -> (259,259,259), into d_out (final)
        constexpr int P = 259 * 259, Q = 1;
        constexpr int tot = P * NO * Q;
        sweep_kernel<P, Q><<<(tot + 255) / 256, 256, 0, stream>>>(A2, out, W);
    }
}

// Round 3
// 734.926 us; speedup vs baseline: 2.0608x; 2.0608x over previous
//
#include <hip/hip_runtime.h>

// Natural cubic spline coefficients (Habermann-Kindermann), 3 axis sweeps.
// tridiag(1,4,1)^-1 decays as (2-sqrt(3))^|i-j| (~2e-10 at distance 16),
// so each output c[j] is a 35-tap linear functional of consecutive inputs
// y[lo_j .. lo_j+34], lo_j = clamp(j-17, 0, 222). ALL boundary handling
// (b1/b2 fixups, rows j=0,1,257,258) is folded into the weight table V,
// giving a branch-free fixed-trip unrolled FMA loop (round-2 lesson:
// runtime trip counts compiled to 8 VGPRs and serialized loads -> 700us).

#define NT 35    // taps per output
#define NO 259   // outputs per line (n+3, n=256)

// Build V[259][35] in fp64. Exact inverse of tridiag(1,4,1) (m=255):
// T(i,t) = (-1)^(i+t) th[min(i,t)] th[254-max(i,t)] / th[255],
// th_k = 4 th_{k-1} - th_{k-2}, th_0=1, th_1=4  (th_255 ~ 1e145, fp64-safe).
__global__ void build_v_kernel(float* __restrict__ V) {
    __shared__ double th[256];
    if (threadIdx.x == 0) {
        th[0] = 1.0; th[1] = 4.0;
        for (int k = 2; k < 256; ++k) th[k] = 4.0 * th[k - 1] - th[k - 2];
    }
    __syncthreads();
    const double thm = th[255];
    auto T = [&](int i, int t) -> double {
        int a = i < t ? i : t;
        int b = i < t ? t : i;
        double v = th[a] * th[254 - b] / thm;
        return ((i + t) & 1) ? -v : v;
    };
    for (int idx = threadIdx.x; idx < NO * NT; idx += blockDim.x) {
        int j  = idx / NT;
        int k  = idx - j * NT;
        int lo = j - 17; lo = lo < 0 ? 0 : (lo > 222 ? 222 : lo);
        int m  = lo + k;                     // y-index this tap multiplies
        double w;
        if (j == 1) {
            w = (m == 0)   ? 1.0 / 6.0 : 0.0;        // c[1] = y[0]/6
        } else if (j == 257) {
            w = (m == 256) ? 1.0 / 6.0 : 0.0;        // c[n+1] = y[256]/6
        } else {
            int i = (j == 0) ? 0 : ((j == 258) ? 254 : j - 2);
            // sol[i] = sum_t T(i,t) B[t],  B[t] = y[t+1] - (t==0) y[0]/6
            //                                           - (t==254) y[256]/6
            double S = 0.0;
            if (m >= 1 && m <= 255) S += T(i, m - 1);
            if (m == 0)             S -= T(i, 0)   / 6.0;
            if (m == 256)           S -= T(i, 254) / 6.0;
            if (j == 0)        w = (m == 0   ? 2.0 / 6.0 : 0.0) - S; // 2b1 - sol[0]
            else if (j == 258) w = (m == 256 ? 2.0 / 6.0 : 0.0) - S; // 2b2 - sol[254]
            else               w = S;
        }
        V[idx] = (float)w;
    }
}

// One sweep along the middle axis of (P, 257, Q) -> (P, 259, Q).
// One thread per OUTPUT element; fixed 35-tap branch-free FMA loop.
template <int P, int Q>
__global__ __launch_bounds__(256) void sweep_kernel(const float* __restrict__ in,
                                                    float* __restrict__ out,
                                                    const float* __restrict__ V) {
    constexpr int TOT = P * NO * Q;
    int tid = blockIdx.x * 256 + threadIdx.x;
    if (tid >= TOT) return;

    int q   = tid % Q;
    int rem = tid / Q;
    int j   = rem % NO;
    int p   = rem / NO;
    int lo  = j - 17; lo = lo < 0 ? 0 : (lo > 222 ? 222 : lo);

    const float* __restrict__ y = in + (size_t)p * 257 * Q + (size_t)lo * Q + q;
    const float* __restrict__ w = V + j * NT;

    float s = 0.f;
#pragma unroll
    for (int k = 0; k < NT; ++k)
        s = fmaf(w[k], y[(size_t)k * Q], s);

    out[tid] = s;   // tid == p*NO*Q + j*Q + q
}

extern "C" void kernel_launch(void* const* d_in, const int* in_sizes, int n_in,
                              void* d_out, int out_size, void* d_ws, size_t ws_size,
                              hipStream_t stream) {
    const float* Y = (const float*)d_in[0];
    float* out = (float*)d_out;
    float* V   = (float*)d_ws;
    float* A2  = (float*)((char*)d_ws + (1 << 20));  // intermediate, after V table

    build_v_kernel<<<1, 256, 0, stream>>>(V);

    {   // axis 0: (257,257,257) -> (259,257,257), into d_out (scratch)
        constexpr int P = 1, Q = 257 * 257;
        constexpr int tot = P * NO * Q;
        sweep_kernel<P, Q><<<(tot + 255) / 256, 256, 0, stream>>>(Y, out, V);
    }
    {   // axis 1: (259,257,257) -> (259,259,257), into ws
        constexpr int P = 259, Q = 257;
        constexpr int tot = P * NO * Q;
        sweep_kernel<P, Q><<<(tot + 255) / 256, 256, 0, stream>>>(out, A2, V);
    }
    {   // axis 2: (259,259,257) -> (259,259,259), into d_out (final)
        constexpr int P = 259 * 259, Q = 1;
        constexpr int tot = P * NO * Q;
        sweep_kernel<P, Q><<<(tot + 255) / 256, 256, 0, stream>>>(A2, out, V);
    }
}

// Round 6
// 353.751 us; speedup vs baseline: 4.2814x; 2.0775x over previous
//
#include <hip/hip_runtime.h>

// Natural cubic spline coefficients, 3 rotated sweeps.
// Each sweep: (A=257, Q) -> (Q, NO=259), sweeping the OUTER axis and writing
// the swept index innermost. 3 sweeps rotate layout back to row-major.
// Each thread computes RJ=16 consecutive j from one 50-float register window;
// weights are block-uniform (s_load). Stores transposed through LDS.

#define NT 50    // register window per thread (covers all taps of its 16 j's)
#define NO 259
#define RJ 16
#define JB 17    // ceil(259/16)

__device__ __host__ inline int win_base(int jb) {
    int b = 16 * jb - 17;
    return b < 0 ? 0 : (b > 207 ? 207 : b);
}

// U[j][k] (k=0..49): weight of y[win_base(j/16)+k] in output c[j], exact fp64
// inverse of tridiag(1,4,1) (m=255) with all boundary rows folded in.
// T(i,t) = (-1)^(i+t) th[min] th[254-max] / th[255], th_k = 4th_{k-1}-th_{k-2}.
__global__ void build_u_kernel(float* __restrict__ U) {
    __shared__ double th[256];
    if (threadIdx.x == 0) {
        th[0] = 1.0; th[1] = 4.0;
        for (int k = 2; k < 256; ++k) th[k] = 4.0 * th[k - 1] - th[k - 2];
    }
    __syncthreads();
    const double thm = th[255];
    auto T = [&](int i, int t) -> double {
        int a = i < t ? i : t;
        int b = i < t ? t : i;
        double v = th[a] * th[254 - b] / thm;
        return ((i + t) & 1) ? -v : v;
    };
    for (int idx = threadIdx.x; idx < NO * NT; idx += blockDim.x) {
        int j  = idx / NT;
        int k  = idx - j * NT;
        int m  = win_base(j / RJ) + k;       // y-index this tap multiplies (<=256 always)
        double w;
        if (j == 1) {
            w = (m == 0)   ? 1.0 / 6.0 : 0.0;
        } else if (j == 257) {
            w = (m == 256) ? 1.0 / 6.0 : 0.0;
        } else {
            int i = (j == 0) ? 0 : ((j == 258) ? 254 : j - 2);
            double S = 0.0;
            if (m >= 1 && m <= 255) S += T(i, m - 1);      // B[t]=y[t+1]
            if (m == 0)             S -= T(i, 0)   / 6.0;  // B[0]   -= y[0]/6
            if (m == 256)           S -= T(i, 254) / 6.0;  // B[254] -= y[256]/6
            if (j == 0)        w = (m == 0   ? 2.0 / 6.0 : 0.0) - S;
            else if (j == 258) w = (m == 256 ? 2.0 / 6.0 : 0.0) - S;
            else               w = S;
        }
        U[idx] = (float)w;
    }
}

// One rotated sweep: in (A=257, Q) outer-axis lines -> out (Q, NO).
template <int Q>
__global__ __launch_bounds__(256) void sweep_rot(const float* __restrict__ in,
                                                 float* __restrict__ out,
                                                 const float* __restrict__ U) {
    __shared__ float lds[RJ * 257];          // [j'][q_local], +1 pad vs 256
    const int t    = threadIdx.x;
    const int q    = blockIdx.x * 256 + t;
    const int jb   = blockIdx.y;
    const int j0   = jb * RJ;
    const int base = win_base(jb);

    float acc[RJ];
    if (q < Q) {
        const float* __restrict__ y = in + (size_t)base * Q + q;
        float win[NT];
#pragma unroll
        for (int k = 0; k < NT; ++k) win[k] = y[(size_t)k * Q];   // coalesced
        const float* __restrict__ w = U + j0 * NT;                // wave-uniform
#pragma unroll
        for (int r = 0; r < RJ; ++r) {
            float s = 0.f;
#pragma unroll
            for (int k = 0; k < NT; ++k)
                s = fmaf(w[r * NT + k], win[k], s);
            acc[r] = s;
        }
    } else {
#pragma unroll
        for (int r = 0; r < RJ; ++r) acc[r] = 0.f;
    }
#pragma unroll
    for (int r = 0; r < RJ; ++r) lds[r * 257 + t] = acc[r];       // conflict-free
    __syncthreads();
    // store transposed: flat f = s*256+t, q' = f>>4, j' = f&15 -> 64B runs
#pragma unroll
    for (int s = 0; s < RJ; ++s) {
        int f  = s * 256 + t;
        int qp = f >> 4;
        int jp = f & 15;
        int qg = blockIdx.x * 256 + qp;
        int j  = j0 + jp;
        if (qg < Q && j < NO)
            out[(size_t)qg * NO + j] = lds[jp * 257 + qp];
    }
}

extern "C" void kernel_launch(void* const* d_in, const int* in_sizes, int n_in,
                              void* d_out, int out_size, void* d_ws, size_t ws_size,
                              hipStream_t stream) {
    const float* Y = (const float*)d_in[0];
    float* out = (float*)d_out;
    float* U   = (float*)d_ws;
    float* A2  = (float*)((char*)d_ws + (1 << 16));   // intermediate after U

    build_u_kernel<<<1, 256, 0, stream>>>(U);

    // S1: sweep x of (x,y,z) -> layout (y,z,x'), into d_out (scratch, 68.4MB)
    {
        constexpr int Q = 257 * 257;
        dim3 grid((Q + 255) / 256, JB, 1);
        sweep_rot<Q><<<grid, 256, 0, stream>>>(Y, out, U);
    }
    // S2: sweep y of (y,z,x') -> layout (z,x',y'), into ws (68.97MB)
    {
        constexpr int Q = 257 * 259;
        dim3 grid((Q + 255) / 256, JB, 1);
        sweep_rot<Q><<<grid, 256, 0, stream>>>(out, A2, U);
    }
    // S3: sweep z of (z,x',y') -> layout (x',y',z') = row-major final, d_out
    {
        constexpr int Q = 259 * 259;
        dim3 grid((Q + 255) / 256, JB, 1);
        sweep_rot<Q><<<grid, 256, 0, stream>>>(A2, out, U);
    }
}